// Round 19
// baseline (389.518 us; speedup 1.0000x reference)
//
#include <hip/hip_runtime.h>
#include <stdint.h>

// B=1024, T=187, H=256, C=5. Fully-fused persistent 2-layer RNN + FC.
// Transposed recurrence: ht = h^T in LDS as [batch col][feature]; state is
// the MFMA B-operand, weights (A-operand f16 frags) register-resident.
//
// R21 GEOMETRY: 64 blocks x 16 batch cols, **16 waves** (1024 thr), each
// wave owns a 16-feature M-slice -> 4 waves/SIMD.
//
// WHY (measured): R16 (8 waves, 308us) has NO pipe >50% (MfmaUtil 9.6,
//   VALU 13.3, LDS ~46%) -> latency-bound serial recurrence. R20 proved
//   bank conflicts immaterial (7,851,968 bit-identical across layouts =
//   free 2-way write aliasing; old read pattern already uniform 8/bank).
//   Less TLP failed (1 w/SIMD: 425-528us). More TLP never tested: 32-feat
//   waves need 192 regs (can't fit 128); 16-feat waves need 96 -> FITS:
//   AGPR(pinned) = wi1 32 + wh1 32 = 64 = AGPR half exactly;
//   arch = wh0 32 + ai 4 + ah0/ah1 4 + B-frags + misc ~= 60-70 vs 64.
// Known cost: per-CU B-reads double (read:MFMA ratio worsens at M=16) ->
//   LDS-throughput floor ~3456 cyc/step ~= 270us. Latency upside ~240us.
// PREDICT: VGPR ~64; Occupancy ~11.5%; MfmaUtil 15-20; dur 240-280us;
//   WRITE_SIZE <= 7MB (small spill ok; >7MB = arch overflow).
// KILL: dur >= 308 -> TLP refuted; resubmit R16 as final deliverable.
// (R13 lesson: full #pragma unroll always. R18 lesson: accumulators die
//  before the next set is born.)

#define Bsz 1024
#define Tt  187
#define Hh  256
#define Cc  5
#define ST  264      // f16 elems per batch-col row (256 + 8 pad)
#define XS  188      // x LDS stride (187 + 1)
#define NT  1024     // threads per block (16 waves)

typedef _Float16 f16x8 __attribute__((ext_vector_type(8)));
typedef __fp16   fp16x2 __attribute__((ext_vector_type(2)));  // cvt_pkrtz native type
typedef float    f32x4 __attribute__((ext_vector_type(4)));

// Force a fragment into the AGPR half of the unified file (R11/R15/R16-proven).
#define PIN_AGPR(v) asm volatile("" : "+a"(v))

__device__ __forceinline__ float tanh_fast(float z) {
    float e = __expf(2.0f * z);
    return 1.0f - 2.0f * __builtin_amdgcn_rcpf(1.0f + e);
}

__device__ __forceinline__ unsigned pk2(float a, float b) {
    union { fp16x2 h; unsigned u; } v;
    v.h = __builtin_amdgcn_cvt_pkrtz(a, b);
    return v.u;
}

__global__ void __launch_bounds__(NT, 4)
rnn_fused(const float* __restrict__ x,     // [B][T]
          const float* __restrict__ Wih0,  // [H][1]
          const float* __restrict__ Whh0,  // [H][H]
          const float* __restrict__ bih0,
          const float* __restrict__ bhh0,
          const float* __restrict__ Wih1,  // [H][H]
          const float* __restrict__ Whh1,  // [H][H]
          const float* __restrict__ bih1,
          const float* __restrict__ bhh1,
          const float* __restrict__ Wfc,   // [C][H]
          const float* __restrict__ bfc,   // [C]
          float* __restrict__ out)         // [B][C]
{
    __shared__ __align__(16) _Float16 ht0[2][16 * ST];
    __shared__ __align__(16) _Float16 ht1[2][16 * ST];
    __shared__ float xs[16 * XS];
    __shared__ __align__(16) float bias_lds[3 * Hh];  // [0]=b0sum [1]=b1sum [2]=wi0

    const int tid  = threadIdx.x;
    const int lane = tid & 63;
    const int w    = tid >> 6;     // wave 0..15 -> features [16w, 16w+16)
    const int q    = lane >> 4;
    const int c    = lane & 15;    // batch col within block
    const int bb   = blockIdx.x * 16;

    // ---- one-time: stage weight A-fragments (f16), 16 features/wave ----
    // A-layout: lane (q,c) reg j holds A[m=16w+c][k=kt*32+q*8+j].
    // wi1, wh1 -> AGPR half (pinned, 64 exactly). wh0 -> arch VGPRs (32).
    f16x8 wh0[8], wi1[8], wh1[8];
    {
        const int m = 16 * w + c;
#pragma unroll
        for (int kt = 0; kt < 8; ++kt) {
            const int off = m * Hh + kt * 32 + q * 8;
            {
                const float4 a0 = *(const float4*)(Whh0 + off);
                const float4 a1 = *(const float4*)(Whh0 + off + 4);
                wh0[kt] = (f16x8){(_Float16)a0.x, (_Float16)a0.y, (_Float16)a0.z, (_Float16)a0.w,
                                  (_Float16)a1.x, (_Float16)a1.y, (_Float16)a1.z, (_Float16)a1.w};
            }
            {
                const float4 a0 = *(const float4*)(Wih1 + off);
                const float4 a1 = *(const float4*)(Wih1 + off + 4);
                wi1[kt] = (f16x8){(_Float16)a0.x, (_Float16)a0.y, (_Float16)a0.z, (_Float16)a0.w,
                                  (_Float16)a1.x, (_Float16)a1.y, (_Float16)a1.z, (_Float16)a1.w};
                PIN_AGPR(wi1[kt]);
            }
            {
                const float4 a0 = *(const float4*)(Whh1 + off);
                const float4 a1 = *(const float4*)(Whh1 + off + 4);
                wh1[kt] = (f16x8){(_Float16)a0.x, (_Float16)a0.y, (_Float16)a0.z, (_Float16)a0.w,
                                  (_Float16)a1.x, (_Float16)a1.y, (_Float16)a1.z, (_Float16)a1.w};
                PIN_AGPR(wh1[kt]);
            }
        }
    }

    // ---- init LDS: x tile, biases, ht1 = 0 (both buffers), ht0[0] ----
    for (int i = tid; i < 16 * Tt; i += NT) {
        const int b = i / Tt, t = i - b * Tt;
        xs[b * XS + t] = x[(bb + b) * Tt + t];
    }
    if (tid < Hh) {
        bias_lds[tid]           = bih0[tid] + bhh0[tid];
        bias_lds[Hh + tid]      = bih1[tid] + bhh1[tid];
        bias_lds[2 * Hh + tid]  = Wih0[tid];
    }
    {
        _Float16* z = &ht1[0][0];
        for (int i = tid; i < 2 * 16 * ST; i += NT) z[i] = (_Float16)0.f;
    }
    for (int i = tid; i < 16 * Hh; i += NT) {
        const int b = i >> 8, f = i & 255;
        const float xv0 = x[(bb + b) * Tt];
        ht0[0][b * ST + f] =
            (_Float16)tanh_fast(xv0 * Wih0[f] + bih0[f] + bhh0[f]);
    }
    __syncthreads();

    // B-operand read base: lane (q,c) reg j needs ht[k=kt*32+q*8+j][col c]
    const int rdoff = c * ST + q * 8;
    const int wroff = c * ST + 16 * w + 4 * q;   // D write: [c][16w+4q .. +3]
    const int fq    = 16 * w + 4 * q;            // bias base

    // ---- main recurrence, time-skewed (R16 phase order):
    // step s: B0 = ht0[s]; produce ht0[s+1] (Whh0) and ht1[s] (Wih1 + Whh1)
#pragma unroll 1
    for (int s = 0; s < Tt; ++s) {
        const int cur = s & 1, nxt = cur ^ 1;
        const _Float16* B0p = &ht0[cur][rdoff];
        const _Float16* B1p = &ht1[nxt][rdoff];   // ht1[s-1]
        int sn = s + 1; if (sn >= Tt) sn = Tt - 1;  // last h0_next unused
        const float xv = xs[c * XS + sn];

        const f32x4 z4 = (f32x4){0.f, 0.f, 0.f, 0.f};

        // -- l0 MFMA: ai = Wih1 . ht0 ; ah0 = Whh0 . ht0 (shared B-frag)
        f32x4 ai  = z4;
        f32x4 ah0 = z4;
#pragma unroll
        for (int kt = 0; kt < 8; ++kt) {
            const f16x8 B = *(const f16x8*)(B0p + kt * 32);
            ai  = __builtin_amdgcn_mfma_f32_16x16x32_f16(wi1[kt], B, ai,  0, 0, 0);
            ah0 = __builtin_amdgcn_mfma_f32_16x16x32_f16(wh0[kt], B, ah0, 0, 0, 0);
        }

        // -- l0 finish: ht0[s+1] = tanh(ah0 + b0 + x_{s+1}*wi0); ah0 dies
        {
            const float4 b0r = *(const float4*)&bias_lds[fq];
            const float4 w0r = *(const float4*)&bias_lds[2 * Hh + fq];
            const float t0 = tanh_fast(ah0[0] + b0r.x + xv * w0r.x);
            const float t1 = tanh_fast(ah0[1] + b0r.y + xv * w0r.y);
            const float t2 = tanh_fast(ah0[2] + b0r.z + xv * w0r.z);
            const float t3 = tanh_fast(ah0[3] + b0r.w + xv * w0r.w);
            *(uint2*)(&ht0[nxt][wroff]) = make_uint2(pk2(t0, t1), pk2(t2, t3));
        }

        // -- l1 MFMA: ah1 = Whh1 . ht1[s-1] (independent chain)
        f32x4 ah1 = z4;
#pragma unroll
        for (int kt = 0; kt < 8; ++kt) {
            const f16x8 B = *(const f16x8*)(B1p + kt * 32);
            ah1 = __builtin_amdgcn_mfma_f32_16x16x32_f16(wh1[kt], B, ah1, 0, 0, 0);
        }

        // -- l1 finish: ht1[s] = tanh(ai + ah1 + b1)
        {
            const float4 b1r = *(const float4*)&bias_lds[Hh + fq];
            const float t0 = tanh_fast(ai[0] + ah1[0] + b1r.x);
            const float t1 = tanh_fast(ai[1] + ah1[1] + b1r.y);
            const float t2 = tanh_fast(ai[2] + ah1[2] + b1r.z);
            const float t3 = tanh_fast(ai[3] + ah1[3] + b1r.w);
            *(uint2*)(&ht1[cur][wroff]) = make_uint2(pk2(t0, t1), pk2(t2, t3));
        }
        __syncthreads();   // double-buffered: one barrier per step
    }

    // ---- FC epilogue: out[bb+b][cls] = ht1_final[.][b] . Wfc[cls] + bfc ----
    if (tid < 16 * Cc) {
        const int b = tid / Cc, cls = tid - Cc * (tid / Cc);
        const _Float16* h = &ht1[(Tt - 1) & 1][b * ST];
        float acc = bfc[cls];
        for (int k = 0; k < Hh; ++k)
            acc += (float)h[k] * Wfc[cls * Hh + k];
        out[(bb + b) * Cc + cls] = acc;
    }
}

extern "C" void kernel_launch(void* const* d_in, const int* in_sizes, int n_in,
                              void* d_out, int out_size, void* d_ws, size_t ws_size,
                              hipStream_t stream) {
    rnn_fused<<<dim3(Bsz / 16), dim3(NT), 0, stream>>>(
        (const float*)d_in[0],  // x
        (const float*)d_in[1],  // W_ih0
        (const float*)d_in[2],  // W_hh0
        (const float*)d_in[3],  // b_ih0
        (const float*)d_in[4],  // b_hh0
        (const float*)d_in[5],  // W_ih1
        (const float*)d_in[6],  // W_hh1
        (const float*)d_in[7],  // b_ih1
        (const float*)d_in[8],  // b_hh1
        (const float*)d_in[9],  // W_fc
        (const float*)d_in[10], // b_fc
        (float*)d_out);
}

// Round 20
// 369.675 us; speedup vs baseline: 1.0537x; 1.0537x over previous
//
#include <hip/hip_runtime.h>
#include <stdint.h>

// B=1024, T=187, H=256, C=5. Fully-fused persistent 2-layer RNN + FC.
// FINAL KERNEL (R16, measured 308us) — restored after the full experiment
// matrix closed at a latency-bound plateau:
//   Register/residency: max-spill 318 / no-spill-8wave 308 (THIS) /
//     no-spill-16wave 331 / 1-wave-per-SIMD 425-528.
//   Schedule: R16 order 308 (THIS) / skew 335 / reorder 362 / chained 334.
//   Layout: padded 308 (THIS) / XOR-swizzled 310 — bank conflicts proven
//     immaterial (counter tracks traffic, not stalls).
//   TLP: 2 waves/SIMD optimal; 1 and 4 both worse.
// All correct variants land 308-335us: serial dependency chain floor
// (187 x {ds_read -> 8-deep MFMA chain -> tanh -> LDS write -> barrier}
// ~= 3950 cyc/step) with no pipe >50%. Next escape would be cross-block
// pipelining through L2 (coherence-risk redesign) — not attempted.
//
// STRUCTURE: transposed recurrence, ht = h^T in LDS [batch col][feature];
// state = MFMA B-operand; weights = A-operand f16 frags, fully register-
// resident: wi1+wh1 pinned to the AGPR half (asm "+a", 128 regs exactly),
// wh0 in arch VGPRs; biases/wi0 in LDS (keeps arch <= 128, no loop spill).
// 64 blocks x 16 batch cols, 8 waves x 32-feature M-slice, double-buffered
// state, one barrier/step.
// REGISTER MODEL (measured): 512 unified regs/SIMD; per-wave budget =
// 512/waves-per-SIMD, split half arch / half AGPR; compiler never spills
// into idle AGPRs; "+a" pins claim them. Full #pragma unroll mandatory
// (partial unroll -> runtime index -> arrays demoted to scratch, 2107us).

#define Bsz 1024
#define Tt  187
#define Hh  256
#define Cc  5
#define ST  264      // f16 elems per batch-col row (256 + 8 pad)
#define XS  188      // x LDS stride (187 + 1)

typedef _Float16 f16x8 __attribute__((ext_vector_type(8)));
typedef __fp16   fp16x2 __attribute__((ext_vector_type(2)));  // cvt_pkrtz native type
typedef float    f32x4 __attribute__((ext_vector_type(4)));

// Force a fragment into the AGPR half of the unified file.
#define PIN_AGPR(v) asm volatile("" : "+a"(v))

__device__ __forceinline__ float tanh_fast(float z) {
    float e = __expf(2.0f * z);
    return 1.0f - 2.0f * __builtin_amdgcn_rcpf(1.0f + e);
}

__device__ __forceinline__ unsigned pk2(float a, float b) {
    union { fp16x2 h; unsigned u; } v;
    v.h = __builtin_amdgcn_cvt_pkrtz(a, b);
    return v.u;
}

__global__ void __launch_bounds__(512, 2)
rnn_fused(const float* __restrict__ x,     // [B][T]
          const float* __restrict__ Wih0,  // [H][1]
          const float* __restrict__ Whh0,  // [H][H]
          const float* __restrict__ bih0,
          const float* __restrict__ bhh0,
          const float* __restrict__ Wih1,  // [H][H]
          const float* __restrict__ Whh1,  // [H][H]
          const float* __restrict__ bih1,
          const float* __restrict__ bhh1,
          const float* __restrict__ Wfc,   // [C][H]
          const float* __restrict__ bfc,   // [C]
          float* __restrict__ out)         // [B][C]
{
    __shared__ __align__(16) _Float16 ht0[2][16 * ST];
    __shared__ __align__(16) _Float16 ht1[2][16 * ST];
    __shared__ float xs[16 * XS];
    __shared__ __align__(16) float bias_lds[3 * Hh];  // [0]=b0sum [1]=b1sum [2]=wi0

    const int tid  = threadIdx.x;
    const int lane = tid & 63;
    const int w    = tid >> 6;     // wave 0..7 -> features [32w, 32w+32)
    const int q    = lane >> 4;
    const int c    = lane & 15;    // batch col within block
    const int bb   = blockIdx.x * 16;

    // ---- one-time: stage weight A-fragments (f16) ----
    // wi1, wh1 -> AGPR half (pinned, 128 exactly). wh0 -> arch VGPRs (64).
    f16x8 wh0[2][8], wi1[2][8], wh1[2][8];
#pragma unroll
    for (int mt = 0; mt < 2; ++mt) {
        const int fb = 32 * w + 16 * mt;
        const int m = fb + c;
#pragma unroll
        for (int kt = 0; kt < 8; ++kt) {
            const int off = m * Hh + kt * 32 + q * 8;
            {
                const float4 a0 = *(const float4*)(Whh0 + off);
                const float4 a1 = *(const float4*)(Whh0 + off + 4);
                wh0[mt][kt] = (f16x8){(_Float16)a0.x, (_Float16)a0.y, (_Float16)a0.z, (_Float16)a0.w,
                                      (_Float16)a1.x, (_Float16)a1.y, (_Float16)a1.z, (_Float16)a1.w};
            }
            {
                const float4 a0 = *(const float4*)(Wih1 + off);
                const float4 a1 = *(const float4*)(Wih1 + off + 4);
                wi1[mt][kt] = (f16x8){(_Float16)a0.x, (_Float16)a0.y, (_Float16)a0.z, (_Float16)a0.w,
                                      (_Float16)a1.x, (_Float16)a1.y, (_Float16)a1.z, (_Float16)a1.w};
                PIN_AGPR(wi1[mt][kt]);
            }
            {
                const float4 a0 = *(const float4*)(Whh1 + off);
                const float4 a1 = *(const float4*)(Whh1 + off + 4);
                wh1[mt][kt] = (f16x8){(_Float16)a0.x, (_Float16)a0.y, (_Float16)a0.z, (_Float16)a0.w,
                                      (_Float16)a1.x, (_Float16)a1.y, (_Float16)a1.z, (_Float16)a1.w};
                PIN_AGPR(wh1[mt][kt]);
            }
        }
    }

    // ---- init LDS: x tile, biases, ht1 = 0 (both buffers), ht0[0] ----
    for (int i = tid; i < 16 * Tt; i += 512) {
        const int b = i / Tt, t = i - b * Tt;
        xs[b * XS + t] = x[(bb + b) * Tt + t];
    }
    if (tid < Hh) {
        bias_lds[tid]           = bih0[tid] + bhh0[tid];
        bias_lds[Hh + tid]      = bih1[tid] + bhh1[tid];
        bias_lds[2 * Hh + tid]  = Wih0[tid];
    }
    {
        _Float16* z = &ht1[0][0];
        for (int i = tid; i < 2 * 16 * ST; i += 512) z[i] = (_Float16)0.f;
    }
    for (int i = tid; i < 16 * Hh; i += 512) {
        const int b = i >> 8, f = i & 255;
        const float xv0 = x[(bb + b) * Tt];
        ht0[0][b * ST + f] =
            (_Float16)tanh_fast(xv0 * Wih0[f] + bih0[f] + bhh0[f]);
    }
    __syncthreads();

    // B-operand read base: lane (q,c) reg j needs ht[k=kt*32+q*8+j][col c]
    const int rdoff = c * ST + q * 8;
    const int wroff = c * ST + 32 * w + 4 * q;   // D write: [c][fb+4q .. +3]
    const int fq    = 32 * w + 4 * q;            // bias base for mt=0 (+16 for mt=1)

    // ---- main recurrence, time-skewed:
    // step s: B0 = ht0[s]; produce ht0[s+1] (Whh0) and ht1[s] (Wih1 + Whh1)
#pragma unroll 1
    for (int s = 0; s < Tt; ++s) {
        const int cur = s & 1, nxt = cur ^ 1;
        const _Float16* B0p = &ht0[cur][rdoff];
        const _Float16* B1p = &ht1[nxt][rdoff];   // ht1[s-1]
        int sn = s + 1; if (sn >= Tt) sn = Tt - 1;  // last h0_next unused
        const float xv = xs[c * XS + sn];

        // layer0: ai = Wih1 . ht0 ; ah0 = Whh0 . ht0 (shared B-frag).
        // Zero C-in; biases added at tanh (identical f32 adds).
        const f32x4 z4 = (f32x4){0.f, 0.f, 0.f, 0.f};
        f32x4 ai[2]  = {z4, z4};
        f32x4 ah0[2] = {z4, z4};
#pragma unroll
        for (int kt = 0; kt < 8; ++kt) {
            const f16x8 B = *(const f16x8*)(B0p + kt * 32);
            ai[0]  = __builtin_amdgcn_mfma_f32_16x16x32_f16(wi1[0][kt], B, ai[0],  0, 0, 0);
            ai[1]  = __builtin_amdgcn_mfma_f32_16x16x32_f16(wi1[1][kt], B, ai[1],  0, 0, 0);
            ah0[0] = __builtin_amdgcn_mfma_f32_16x16x32_f16(wh0[0][kt], B, ah0[0], 0, 0, 0);
            ah0[1] = __builtin_amdgcn_mfma_f32_16x16x32_f16(wh0[1][kt], B, ah0[1], 0, 0, 0);
        }
        // ht0[s+1] = tanh(ah0 + b0 + x_{s+1} * wi0), pack f16, 8B LDS writes
#pragma unroll
        for (int mt = 0; mt < 2; ++mt) {
            const float4 b0r = *(const float4*)&bias_lds[fq + 16 * mt];
            const float4 w0r = *(const float4*)&bias_lds[2 * Hh + fq + 16 * mt];
            const float t0 = tanh_fast(ah0[mt][0] + b0r.x + xv * w0r.x);
            const float t1 = tanh_fast(ah0[mt][1] + b0r.y + xv * w0r.y);
            const float t2 = tanh_fast(ah0[mt][2] + b0r.z + xv * w0r.z);
            const float t3 = tanh_fast(ah0[mt][3] + b0r.w + xv * w0r.w);
            *(uint2*)(&ht0[nxt][wroff + 16 * mt]) = make_uint2(pk2(t0, t1), pk2(t2, t3));
        }

        // layer1: ah1 = Whh1 . ht1[s-1]; weights AGPR-resident
        f32x4 ah1[2] = {z4, z4};
#pragma unroll
        for (int kt = 0; kt < 8; ++kt) {
            const f16x8 B = *(const f16x8*)(B1p + kt * 32);
            ah1[0] = __builtin_amdgcn_mfma_f32_16x16x32_f16(wh1[0][kt], B, ah1[0], 0, 0, 0);
            ah1[1] = __builtin_amdgcn_mfma_f32_16x16x32_f16(wh1[1][kt], B, ah1[1], 0, 0, 0);
        }
        // ht1[s] = tanh(ai + ah1 + b1)
#pragma unroll
        for (int mt = 0; mt < 2; ++mt) {
            const float4 b1r = *(const float4*)&bias_lds[Hh + fq + 16 * mt];
            const float t0 = tanh_fast(ai[mt][0] + ah1[mt][0] + b1r.x);
            const float t1 = tanh_fast(ai[mt][1] + ah1[mt][1] + b1r.y);
            const float t2 = tanh_fast(ai[mt][2] + ah1[mt][2] + b1r.z);
            const float t3 = tanh_fast(ai[mt][3] + ah1[mt][3] + b1r.w);
            *(uint2*)(&ht1[cur][wroff + 16 * mt]) = make_uint2(pk2(t0, t1), pk2(t2, t3));
        }
        __syncthreads();   // double-buffered: one barrier per step
    }

    // ---- FC epilogue: out[bb+b][cls] = ht1_final[.][b] . Wfc[cls] + bfc ----
    if (tid < 16 * Cc) {
        const int b = tid / Cc, cls = tid - Cc * (tid / Cc);
        const _Float16* h = &ht1[(Tt - 1) & 1][b * ST];
        float acc = bfc[cls];
        for (int k = 0; k < Hh; ++k)
            acc += (float)h[k] * Wfc[cls * Hh + k];
        out[(bb + b) * Cc + cls] = acc;
    }
}

extern "C" void kernel_launch(void* const* d_in, const int* in_sizes, int n_in,
                              void* d_out, int out_size, void* d_ws, size_t ws_size,
                              hipStream_t stream) {
    rnn_fused<<<dim3(Bsz / 16), dim3(512), 0, stream>>>(
        (const float*)d_in[0],  // x
        (const float*)d_in[1],  // W_ih0
        (const float*)d_in[2],  // W_hh0
        (const float*)d_in[3],  // b_ih0
        (const float*)d_in[4],  // b_hh0
        (const float*)d_in[5],  // W_ih1
        (const float*)d_in[6],  // W_hh1
        (const float*)d_in[7],  // b_ih1
        (const float*)d_in[8],  // b_hh1
        (const float*)d_in[9],  // W_fc
        (const float*)d_in[10], // b_fc
        (float*)d_out);
}